// Round 9
// baseline (294.688 us; speedup 1.0000x reference)
//
#include <hip/hip_runtime.h>

// SimpleAttention: B=8, S=2048, H=256
// R18: swapped-QK attn. mfma(K,Q) instead of mfma(Q,K) — identical MFMA cost
// (A/B frag lane layouts match), but C-layout becomes lane-q-local:
// lane holds P[q=l15][k=nf*16+quad*4+r]. Savings, all serial-chain:
//   mask: 2x int4 loads/iter (was 8x int), same coalescing
//   P->LDS: 2x b64 stores (was 8x b16), k-contiguous
//   l: one scalar/lane + 2 shfl_xor at end (was 4 regs + 16-lane reduce +
//      sel4/shfl broadcast); epilogue linv directly lane-resident
// Geometry/staging/barriers byte-identical to R14/R17 (proven optimum).

#define B_ 8
#define S_ 2048
#define H_ 256

typedef __attribute__((ext_vector_type(8))) short s16x8;   // 8 bf16 MFMA A/B frag
typedef __attribute__((ext_vector_type(4))) float f32x4;   // MFMA C/D frag
typedef __attribute__((ext_vector_type(4))) unsigned short u16x4;
typedef __attribute__((ext_vector_type(8))) unsigned short u16x8;

#if __has_builtin(__builtin_amdgcn_exp2f)
#define EXP2F(x) __builtin_amdgcn_exp2f(x)
#else
#define EXP2F(x) exp2f(x)
#endif

__device__ __forceinline__ unsigned short f2bf(float f) {
  unsigned int u = __builtin_bit_cast(unsigned int, f);
  u += 0x7fffu + ((u >> 16) & 1u);   // RNE
  return (unsigned short)(u >> 16);
}
__device__ __forceinline__ float bf2f(unsigned short h) {
  unsigned int u = ((unsigned int)h) << 16;
  return __builtin_bit_cast(float, u);
}
__device__ __forceinline__ f32x4 mfma_bf16(s16x8 a, s16x8 b, f32x4 c) {
  return __builtin_amdgcn_mfma_f32_16x16x32_bf16(a, b, c, 0, 0, 0);
}
// async global->LDS, 16B/lane; LDS dest = wave-uniform base + lane*16
__device__ __forceinline__ void async16(const unsigned short* g, unsigned short* l) {
  __builtin_amdgcn_global_load_lds(
      (const __attribute__((address_space(1))) unsigned int*)g,
      (__attribute__((address_space(3))) unsigned int*)l, 16, 0, 0);
}

// ---------------------------------------------------------------------------
// Kernel 0: W[h][n] fp32 -> Wt[n][h] bf16. grid (48): z = bid>>4, tile = bid&15.
// ---------------------------------------------------------------------------
__global__ __launch_bounds__(256) void wt_kernel(
    const float* __restrict__ Wq, const float* __restrict__ Wk,
    const float* __restrict__ Wv, unsigned short* __restrict__ Wt) {
  __shared__ unsigned short tile[64 * 72];
  int z = blockIdx.x >> 4, x = blockIdx.x & 15;
  const float* W = (z == 0) ? Wq : (z == 1) ? Wk : Wv;
  int n0 = (x & 3) * 64, h0 = (x >> 2) * 64;
  int t = threadIdx.x;
#pragma unroll
  for (int j = 0; j < 4; ++j) {
    int c = j * 256 + t;
    int i = c >> 4, ch = c & 15;
    float4 f = *(const float4*)&W[(h0 + i) * 256 + n0 + ch * 4];
    u16x4 p;
    p[0] = f2bf(f.x); p[1] = f2bf(f.y); p[2] = f2bf(f.z); p[3] = f2bf(f.w);
    *(u16x4*)&tile[i * 72 + ch * 4] = p;
  }
  __syncthreads();
#pragma unroll
  for (int j = 0; j < 2; ++j) {
    int c = j * 256 + t;
    int nr = c >> 3, ch = c & 7;
    u16x8 o;
#pragma unroll
    for (int k = 0; k < 8; ++k) o[k] = tile[(ch * 8 + k) * 72 + nr];
    *(u16x8*)&Wt[z * 65536 + (n0 + nr) * 256 + h0 + ch * 8] = o;
  }
}

// ---------------------------------------------------------------------------
// Kernel 1: proj (768 blocks). R8 structure + 3-stage W rotation (R17):
// W[c8] issued 2 iters ahead -> barrier drain ~free.
// Q scale = 1/16 * log2(e) so attn can exp2 directly.
// ---------------------------------------------------------------------------
__global__ __launch_bounds__(256) void proj_kernel(
    const float* __restrict__ Xq, const float* __restrict__ Xk,
    const float* __restrict__ Xv, const unsigned short* __restrict__ Wt,
    unsigned short* __restrict__ Qb, unsigned short* __restrict__ Kb,
    unsigned short* __restrict__ Vt) {
  __shared__ unsigned short plds[24576];        // 3 x 16KB W stages (48KB)

  int z = blockIdx.x >> 8;                      // 0..2
  int bx = blockIdx.x & 255;
  const float* X = (z == 0) ? Xq : (z == 1) ? Xk : Xv;
  const unsigned short* Wz = Wt + z * 65536;

  int t = threadIdx.x;
  int w = t >> 6, lane = t & 63, quad = lane >> 4, l15 = lane & 15;
  int m0 = bx * 64;
  const float* xrow = X + (size_t)(m0 + w * 16 + l15) * H_;

  f32x4 zero4 = {0.f, 0.f, 0.f, 0.f};
  f32x4 acc[16];
#pragma unroll
  for (int i = 0; i < 16; ++i) acc[i] = zero4;

  // prologue: issue W tiles 0 and 1 into stages 0,1
#pragma unroll
  for (int pre = 0; pre < 2; ++pre) {
#pragma unroll
    for (int j = 0; j < 4; ++j) {
      int c = j * 256 + t;
      int n = c >> 2, p = c & 3;
      async16(Wz + n * 256 + pre * 32 + ((p ^ ((n >> 1) & 3)) << 3),
              plds + pre * 8192 + j * 2048 + w * 512);
    }
  }
  float4 a0 = *(const float4*)(xrow + quad * 8);
  float4 a1 = *(const float4*)(xrow + quad * 8 + 4);

  for (int c8 = 0; c8 < 8; ++c8) {
    int stage = c8 % 3;
    unsigned short* Wc = plds + stage * 8192;
    __syncthreads();   // W[c8] complete (issued 2 iters ago)

    if (c8 + 2 < 8) {
      unsigned short* Wn = plds + ((c8 + 2) % 3) * 8192;
#pragma unroll
      for (int j = 0; j < 4; ++j) {
        int c = j * 256 + t;
        int n = c >> 2, p = c & 3;
        async16(Wz + n * 256 + (c8 + 2) * 32 + ((p ^ ((n >> 1) & 3)) << 3),
                Wn + j * 2048 + w * 512);
      }
    }
    float4 na0, na1;
    if (c8 < 7) {
      na0 = *(const float4*)(xrow + (c8 + 1) * 32 + quad * 8);
      na1 = *(const float4*)(xrow + (c8 + 1) * 32 + quad * 8 + 4);
    }
    s16x8 af;
    af[0] = (short)f2bf(a0.x); af[1] = (short)f2bf(a0.y);
    af[2] = (short)f2bf(a0.z); af[3] = (short)f2bf(a0.w);
    af[4] = (short)f2bf(a1.x); af[5] = (short)f2bf(a1.y);
    af[6] = (short)f2bf(a1.z); af[7] = (short)f2bf(a1.w);

#pragma unroll
    for (int nf = 0; nf < 16; ++nf) {
      int n = nf * 16 + l15;
      s16x8 bf = *(const s16x8*)&Wc[n * 32 + ((quad ^ ((n >> 1) & 3)) << 3)];
      acc[nf] = mfma_bf16(af, bf, acc[nf]);
    }
    a0 = na0; a1 = na1;
  }
  __syncthreads();   // W stages free; epilogue tile aliases

  // Q scale = (1/sqrt(256)) * log2(e) so attn softmax uses exp2 directly.
  float scale = (z == 0) ? 0.090168439f : 1.0f;
  int b = m0 >> 11, s0 = m0 & 2047;
#pragma unroll
  for (int h = 0; h < 2; ++h) {
    if (h) __syncthreads();
    if (z < 2) {
#pragma unroll
      for (int nf2 = 0; nf2 < 8; ++nf2) {
        int n = nf2 * 16 + l15;
#pragma unroll
        for (int r = 0; r < 4; ++r)
          plds[(w * 16 + quad * 4 + r) * 136 + n] = f2bf(acc[h * 8 + nf2][r] * scale);
      }
      __syncthreads();
      unsigned short* Y = (z == 0) ? Qb : Kb;
#pragma unroll
      for (int j = 0; j < 4; ++j) {
        int c = j * 256 + t;
        int mr = c >> 4, ch = c & 15;
        u16x8 o = *(const u16x8*)&plds[mr * 136 + ch * 8];
        *(u16x8*)&Y[(size_t)(m0 + mr) * H_ + h * 128 + ch * 8] = o;
      }
    } else {
#pragma unroll
      for (int nf2 = 0; nf2 < 8; ++nf2) {
        int dl = nf2 * 16 + l15;
#pragma unroll
        for (int r = 0; r < 4; ++r)
          plds[dl * 72 + (w * 16 + quad * 4 + r)] = f2bf(acc[h * 8 + nf2][r]);
      }
      __syncthreads();
#pragma unroll
      for (int j = 0; j < 4; ++j) {
        int c = j * 256 + t;                 // 0..1023
        int dr = c >> 3, ch = c & 7;         // d row 0..127, 8-s chunk
        u16x8 o = *(const u16x8*)&plds[dr * 72 + ch * 8];
        *(u16x8*)&Vt[((size_t)b * H_ + h * 128 + dr) * S_ + s0 + ch * 8] = o;
      }
    }
  }
}

// ---------------------------------------------------------------------------
// Kernel 2: flash attention, NO-MAX softmax, SWAPPED QK (lane-q-local P).
// R14 geometry: BQ=64 (4 waves x 16q), BK=32, grid (8,32,2), K+V async dbuf,
// 1 barrier/iter, exp2 direct, setprio around MFMA, V swizzle (d>>1)&3.
// sacc[nf][r] = S[q=l15][k=nf*16+quad*4+r]; mask 2x int4; P stored as b64;
// l_r is one scalar per lane (q=l15), reduced by 2 shfl_xor at end.
// ---------------------------------------------------------------------------
__global__ __launch_bounds__(256, 2) void attn_kernel(
    const unsigned short* __restrict__ Qb, const unsigned short* __restrict__ Kb,
    const unsigned short* __restrict__ Vt, const int* __restrict__ mask,
    unsigned short* __restrict__ Op, float* __restrict__ Ml,
    float* __restrict__ out) {
  __shared__ unsigned short lds[35072];   // 2*(8K K + 8K V shorts) + Ps 4*576
  unsigned short* Ps = lds + 32768;       // [wave][16 q][36]

  int t = threadIdx.x;
  int w = t >> 6, lane = t & 63, quad = lane >> 4, l15 = lane & 15;
  int b = blockIdx.x;                     // batch -> XCD affinity
  int q0 = blockIdx.y * 64;
  int split = blockIdx.z, nsplit = gridDim.z;
  int kbeg = (64 * split) / nsplit, kend = (64 * (split + 1)) / nsplit;

  s16x8 qa[8];
  {
    const unsigned short* qp =
        Qb + ((size_t)b * S_ + q0 + w * 16 + l15) * H_ + quad * 8;
#pragma unroll
    for (int c = 0; c < 8; ++c) qa[c] = *(const s16x8*)(qp + 32 * c);
  }

  const unsigned short* Kbb = Kb + (size_t)b * S_ * H_;
  const unsigned short* Vbb = Vt + (size_t)b * H_ * S_;

  int krow = lane >> 5, kch = lane & 31;
  int vrow = lane >> 2, vch = lane & 3;

  f32x4 zero4 = {0.f, 0.f, 0.f, 0.f};
  f32x4 acc[16];
#pragma unroll
  for (int i = 0; i < 16; ++i) acc[i] = zero4;
  float l_r = 0.f;                        // row sum for q = l15 (partial: this quad's k)

  // per-lane mask row: q = q0 + w*16 + l15
  const int* mrow = mask + ((size_t)b * S_ + q0 + w * 16 + l15) * S_;

  {
    int k0 = kbeg * 32;
    unsigned short* Kd = lds;
    unsigned short* Vd = lds + 8192;
#pragma unroll
    for (int j = 0; j < 4; ++j) {
      int key = (w * 4 + j) * 2 + krow;
      async16(Kbb + ((size_t)(k0 + key) << 8) + ((kch ^ (key & 7)) << 3),
              Kd + (w * 4 + j) * 512);
      int d = w * 64 + j * 16 + vrow;
      async16(Vbb + ((size_t)d << 11) + k0 + ((vch ^ ((d >> 1) & 3)) << 3),
              Vd + (w * 64 + j * 16) * 32);
    }
  }
  int4 mw[2];
  mw[0] = *(const int4*)&mrow[kbeg * 32 + quad * 4];
  mw[1] = *(const int4*)&mrow[kbeg * 32 + 16 + quad * 4];

  for (int kt = kbeg; kt < kend; ++kt) {
    int cur = (kt - kbeg) & 1;
    unsigned short* Ksc = lds + cur * 16384;
    unsigned short* Vsc = Ksc + 8192;
    __syncthreads();   // drains buf[cur] asyncs; buf[cur^1] free

    if (kt + 1 < kend) {
      int k0 = (kt + 1) * 32;
      unsigned short* Kd = lds + (cur ^ 1) * 16384;
      unsigned short* Vd = Kd + 8192;
#pragma unroll
      for (int j = 0; j < 4; ++j) {
        int key = (w * 4 + j) * 2 + krow;
        async16(Kbb + ((size_t)(k0 + key) << 8) + ((kch ^ (key & 7)) << 3),
                Kd + (w * 4 + j) * 512);
        int d = w * 64 + j * 16 + vrow;
        async16(Vbb + ((size_t)d << 11) + k0 + ((vch ^ ((d >> 1) & 3)) << 3),
                Vd + (w * 64 + j * 16) * 32);
      }
    }
    int4 mwn[2];
    {
      int ktn = (kt + 1 < kend) ? kt + 1 : kt;
      mwn[0] = *(const int4*)&mrow[ktn * 32 + quad * 4];
      mwn[1] = *(const int4*)&mrow[ktn * 32 + 16 + quad * 4];
    }

    // ---- S^T via swapped operands: mfma(K, Q) -> lane holds S[q=l15][k...]
    f32x4 sacc[2];
    sacc[0] = zero4; sacc[1] = zero4;
    __builtin_amdgcn_s_setprio(1);
#pragma unroll
    for (int c = 0; c < 8; ++c) {
#pragma unroll
      for (int nf = 0; nf < 2; ++nf) {
        int n = nf * 16 + l15;
        s16x8 kb = *(const s16x8*)&Ksc[n * 256 + (((quad + 4 * c) ^ (n & 7)) << 3)];
        sacc[nf] = mfma_bf16(kb, qa[c], sacc[nf]);
      }
    }
    __builtin_amdgcn_s_setprio(0);

    // ---- no-max softmax: p = masked ? 0 : exp2(s); k-contiguous pack
#pragma unroll
    for (int nf = 0; nf < 2; ++nf) {
      float p0 = mw[nf].x ? 0.f : EXP2F(sacc[nf][0]);
      float p1 = mw[nf].y ? 0.f : EXP2F(sacc[nf][1]);
      float p2 = mw[nf].z ? 0.f : EXP2F(sacc[nf][2]);
      float p3 = mw[nf].w ? 0.f : EXP2F(sacc[nf][3]);
      l_r += (p0 + p1) + (p2 + p3);
      u16x4 pk;
      pk[0] = f2bf(p0); pk[1] = f2bf(p1); pk[2] = f2bf(p2); pk[3] = f2bf(p3);
      *(u16x4*)&Ps[w * 576 + l15 * 36 + nf * 16 + quad * 4] = pk;
    }

    // ---- O^T += V^T P^T (no rescale — shift is constant 0)
    {
      s16x8 bp = *(const s16x8*)&Ps[w * 576 + l15 * 36 + quad * 8];
      __builtin_amdgcn_s_setprio(1);
#pragma unroll
      for (int mf = 0; mf < 16; ++mf) {
        int d = mf * 16 + l15;
        s16x8 av = *(const s16x8*)&Vsc[d * 32 + ((quad ^ ((d >> 1) & 3)) << 3)];
        acc[mf] = mfma_bf16(av, bp, acc[mf]);
      }
      __builtin_amdgcn_s_setprio(0);
    }

    mw[0] = mwn[0]; mw[1] = mwn[1];
  }

  // ---- row-sum finish: sum the 4 quad-partials for q = l15
  l_r += __shfl_xor(l_r, 16, 64);
  l_r += __shfl_xor(l_r, 32, 64);

  if (gridDim.z == 1) {
    float linv = (l_r > 0.f) ? (1.0f / l_r) : 0.f;
    float* op = out + ((size_t)b * S_ + q0 + w * 16 + l15) * H_ + quad * 4;
#pragma unroll
    for (int mf = 0; mf < 16; ++mf) {
      float4 o;
      o.x = acc[mf][0] * linv; o.y = acc[mf][1] * linv;
      o.z = acc[mf][2] * linv; o.w = acc[mf][3] * linv;
      *(float4*)(op + mf * 16) = o;
    }
  } else {
    int qg = q0 + w * 16 + l15;
    unsigned short* op =
        Op + (((size_t)split * B_ + b) * S_ + qg) * H_ + quad * 4;
#pragma unroll
    for (int mf = 0; mf < 16; ++mf) {
      u16x4 pk;
      pk[0] = f2bf(acc[mf][0]); pk[1] = f2bf(acc[mf][1]);
      pk[2] = f2bf(acc[mf][2]); pk[3] = f2bf(acc[mf][3]);
      *(u16x4*)(op + mf * 16) = pk;
    }
    if (lane < 16) {
      Ml[((size_t)split * B_ + b) * S_ + q0 + w * 16 + lane] = l_r;
    }
  }
}

// ---------------------------------------------------------------------------
// Kernel 3: combine — out = sum_i O_i / sum_i l_i. grid (512,8) x 1024.
// ---------------------------------------------------------------------------
__global__ __launch_bounds__(1024) void combine_kernel(
    const unsigned short* __restrict__ Op, const float* __restrict__ Ml,
    float* __restrict__ out, int nsplit) {
  int q = blockIdx.x * 4 + (threadIdx.x >> 8);
  int b = blockIdx.y, d = threadIdx.x & 255;
  float osum = 0.f, lsum = 0.f;
  for (int i = 0; i < nsplit; ++i) {
    size_t ro = ((size_t)i * B_ + b) * S_ + q;
    lsum += Ml[ro];
    osum += bf2f(Op[ro * H_ + d]);
  }
  float linv = (lsum > 0.f) ? (1.0f / lsum) : 0.f;
  out[((size_t)b * S_ + q) * H_ + d] = osum * linv;
}

// ---------------------------------------------------------------------------
extern "C" void kernel_launch(void* const* d_in, const int* in_sizes, int n_in,
                              void* d_out, int out_size, void* d_ws, size_t ws_size,
                              hipStream_t stream) {
  const float* k_in = (const float*)d_in[0];
  const float* q_in = (const float*)d_in[1];
  const float* v_in = (const float*)d_in[2];
  const int* mask = (const int*)d_in[3];
  const float* Wq = (const float*)d_in[4];
  const float* Wk = (const float*)d_in[5];
  const float* Wv = (const float*)d_in[6];
  float* out = (float*)d_out;

  unsigned short* Qb = (unsigned short*)d_ws;
  unsigned short* Kb = Qb + (size_t)4194304;
  unsigned short* Vt = Kb + (size_t)4194304;
  unsigned short* Wt = Vt + (size_t)4194304;
  unsigned short* Op = Wt + (size_t)196608;
  float* Ml = (float*)(Op + (size_t)8388608);
  const size_t need = 42467328;
  int nsplit = (ws_size >= need) ? 2 : 1;

  hipLaunchKernelGGL(wt_kernel, dim3(48), dim3(256), 0, stream,
                     Wq, Wk, Wv, Wt);
  hipLaunchKernelGGL(proj_kernel, dim3(768), dim3(256), 0, stream,
                     q_in, k_in, v_in, Wt, Qb, Kb, Vt);
  hipLaunchKernelGGL(attn_kernel, dim3(8, 32, nsplit), dim3(256), 0, stream,
                     Qb, Kb, Vt, mask, Op, Ml, out);
  if (nsplit > 1)
    hipLaunchKernelGGL(combine_kernel, dim3(512, 8), dim3(1024), 0, stream,
                       Op, Ml, out, nsplit);
}

// Round 10
// 286.095 us; speedup vs baseline: 1.0300x; 1.0300x over previous
//
#include <hip/hip_runtime.h>

// SimpleAttention: B=8, S=2048, H=256
// R19: consolidation. attn = R14-exact (84.4us plateau, reproduced 3x; all
// 5 structural variants R11/R12/R15/R16/R18 regressed). proj = R17 3-stage.
// NEW: combine re-tiled for full coalescing — 128 threads x 2 d/thread per
// q-row: uint (2xbf16) reads + float2 writes (was scalar ushort = 2B/lane).

#define B_ 8
#define S_ 2048
#define H_ 256

typedef __attribute__((ext_vector_type(8))) short s16x8;   // 8 bf16 MFMA A/B frag
typedef __attribute__((ext_vector_type(4))) float f32x4;   // MFMA C/D frag
typedef __attribute__((ext_vector_type(4))) unsigned short u16x4;
typedef __attribute__((ext_vector_type(8))) unsigned short u16x8;

#if __has_builtin(__builtin_amdgcn_exp2f)
#define EXP2F(x) __builtin_amdgcn_exp2f(x)
#else
#define EXP2F(x) exp2f(x)
#endif

__device__ __forceinline__ unsigned short f2bf(float f) {
  unsigned int u = __builtin_bit_cast(unsigned int, f);
  u += 0x7fffu + ((u >> 16) & 1u);   // RNE
  return (unsigned short)(u >> 16);
}
__device__ __forceinline__ float bf2f(unsigned short h) {
  unsigned int u = ((unsigned int)h) << 16;
  return __builtin_bit_cast(float, u);
}
__device__ __forceinline__ f32x4 mfma_bf16(s16x8 a, s16x8 b, f32x4 c) {
  return __builtin_amdgcn_mfma_f32_16x16x32_bf16(a, b, c, 0, 0, 0);
}
__device__ __forceinline__ float sel4(const float v[4], int r) {
  float t0 = (r & 1) ? v[1] : v[0];
  float t1 = (r & 1) ? v[3] : v[2];
  return (r & 2) ? t1 : t0;
}
// async global->LDS, 16B/lane; LDS dest = wave-uniform base + lane*16
__device__ __forceinline__ void async16(const unsigned short* g, unsigned short* l) {
  __builtin_amdgcn_global_load_lds(
      (const __attribute__((address_space(1))) unsigned int*)g,
      (__attribute__((address_space(3))) unsigned int*)l, 16, 0, 0);
}

// ---------------------------------------------------------------------------
// Kernel 0: W[h][n] fp32 -> Wt[n][h] bf16. grid (48): z = bid>>4, tile = bid&15.
// ---------------------------------------------------------------------------
__global__ __launch_bounds__(256) void wt_kernel(
    const float* __restrict__ Wq, const float* __restrict__ Wk,
    const float* __restrict__ Wv, unsigned short* __restrict__ Wt) {
  __shared__ unsigned short tile[64 * 72];
  int z = blockIdx.x >> 4, x = blockIdx.x & 15;
  const float* W = (z == 0) ? Wq : (z == 1) ? Wk : Wv;
  int n0 = (x & 3) * 64, h0 = (x >> 2) * 64;
  int t = threadIdx.x;
#pragma unroll
  for (int j = 0; j < 4; ++j) {
    int c = j * 256 + t;
    int i = c >> 4, ch = c & 15;
    float4 f = *(const float4*)&W[(h0 + i) * 256 + n0 + ch * 4];
    u16x4 p;
    p[0] = f2bf(f.x); p[1] = f2bf(f.y); p[2] = f2bf(f.z); p[3] = f2bf(f.w);
    *(u16x4*)&tile[i * 72 + ch * 4] = p;
  }
  __syncthreads();
#pragma unroll
  for (int j = 0; j < 2; ++j) {
    int c = j * 256 + t;
    int nr = c >> 3, ch = c & 7;
    u16x8 o;
#pragma unroll
    for (int k = 0; k < 8; ++k) o[k] = tile[(ch * 8 + k) * 72 + nr];
    *(u16x8*)&Wt[z * 65536 + (n0 + nr) * 256 + h0 + ch * 8] = o;
  }
}

// ---------------------------------------------------------------------------
// Kernel 1: proj (768 blocks). R8 structure + 3-stage W rotation (R17):
// W[c8] issued 2 iters ahead -> barrier drain ~free.
// Q scale = 1/16 * log2(e) so attn can exp2 directly.
// ---------------------------------------------------------------------------
__global__ __launch_bounds__(256) void proj_kernel(
    const float* __restrict__ Xq, const float* __restrict__ Xk,
    const float* __restrict__ Xv, const unsigned short* __restrict__ Wt,
    unsigned short* __restrict__ Qb, unsigned short* __restrict__ Kb,
    unsigned short* __restrict__ Vt) {
  __shared__ unsigned short plds[24576];        // 3 x 16KB W stages (48KB)

  int z = blockIdx.x >> 8;                      // 0..2
  int bx = blockIdx.x & 255;
  const float* X = (z == 0) ? Xq : (z == 1) ? Xk : Xv;
  const unsigned short* Wz = Wt + z * 65536;

  int t = threadIdx.x;
  int w = t >> 6, lane = t & 63, quad = lane >> 4, l15 = lane & 15;
  int m0 = bx * 64;
  const float* xrow = X + (size_t)(m0 + w * 16 + l15) * H_;

  f32x4 zero4 = {0.f, 0.f, 0.f, 0.f};
  f32x4 acc[16];
#pragma unroll
  for (int i = 0; i < 16; ++i) acc[i] = zero4;

  // prologue: issue W tiles 0 and 1 into stages 0,1
#pragma unroll
  for (int pre = 0; pre < 2; ++pre) {
#pragma unroll
    for (int j = 0; j < 4; ++j) {
      int c = j * 256 + t;
      int n = c >> 2, p = c & 3;
      async16(Wz + n * 256 + pre * 32 + ((p ^ ((n >> 1) & 3)) << 3),
              plds + pre * 8192 + j * 2048 + w * 512);
    }
  }
  float4 a0 = *(const float4*)(xrow + quad * 8);
  float4 a1 = *(const float4*)(xrow + quad * 8 + 4);

  for (int c8 = 0; c8 < 8; ++c8) {
    int stage = c8 % 3;
    unsigned short* Wc = plds + stage * 8192;
    __syncthreads();   // W[c8] complete (issued 2 iters ago)

    if (c8 + 2 < 8) {
      unsigned short* Wn = plds + ((c8 + 2) % 3) * 8192;
#pragma unroll
      for (int j = 0; j < 4; ++j) {
        int c = j * 256 + t;
        int n = c >> 2, p = c & 3;
        async16(Wz + n * 256 + (c8 + 2) * 32 + ((p ^ ((n >> 1) & 3)) << 3),
                Wn + j * 2048 + w * 512);
      }
    }
    float4 na0, na1;
    if (c8 < 7) {
      na0 = *(const float4*)(xrow + (c8 + 1) * 32 + quad * 8);
      na1 = *(const float4*)(xrow + (c8 + 1) * 32 + quad * 8 + 4);
    }
    s16x8 af;
    af[0] = (short)f2bf(a0.x); af[1] = (short)f2bf(a0.y);
    af[2] = (short)f2bf(a0.z); af[3] = (short)f2bf(a0.w);
    af[4] = (short)f2bf(a1.x); af[5] = (short)f2bf(a1.y);
    af[6] = (short)f2bf(a1.z); af[7] = (short)f2bf(a1.w);

#pragma unroll
    for (int nf = 0; nf < 16; ++nf) {
      int n = nf * 16 + l15;
      s16x8 bf = *(const s16x8*)&Wc[n * 32 + ((quad ^ ((n >> 1) & 3)) << 3)];
      acc[nf] = mfma_bf16(af, bf, acc[nf]);
    }
    a0 = na0; a1 = na1;
  }
  __syncthreads();   // W stages free; epilogue tile aliases

  // Q scale = (1/sqrt(256)) * log2(e) so attn softmax uses exp2 directly.
  float scale = (z == 0) ? 0.090168439f : 1.0f;
  int b = m0 >> 11, s0 = m0 & 2047;
#pragma unroll
  for (int h = 0; h < 2; ++h) {
    if (h) __syncthreads();
    if (z < 2) {
#pragma unroll
      for (int nf2 = 0; nf2 < 8; ++nf2) {
        int n = nf2 * 16 + l15;
#pragma unroll
        for (int r = 0; r < 4; ++r)
          plds[(w * 16 + quad * 4 + r) * 136 + n] = f2bf(acc[h * 8 + nf2][r] * scale);
      }
      __syncthreads();
      unsigned short* Y = (z == 0) ? Qb : Kb;
#pragma unroll
      for (int j = 0; j < 4; ++j) {
        int c = j * 256 + t;
        int mr = c >> 4, ch = c & 15;
        u16x8 o = *(const u16x8*)&plds[mr * 136 + ch * 8];
        *(u16x8*)&Y[(size_t)(m0 + mr) * H_ + h * 128 + ch * 8] = o;
      }
    } else {
#pragma unroll
      for (int nf2 = 0; nf2 < 8; ++nf2) {
        int dl = nf2 * 16 + l15;
#pragma unroll
        for (int r = 0; r < 4; ++r)
          plds[dl * 72 + (w * 16 + quad * 4 + r)] = f2bf(acc[h * 8 + nf2][r]);
      }
      __syncthreads();
#pragma unroll
      for (int j = 0; j < 4; ++j) {
        int c = j * 256 + t;                 // 0..1023
        int dr = c >> 3, ch = c & 7;         // d row 0..127, 8-s chunk
        u16x8 o = *(const u16x8*)&plds[dr * 72 + ch * 8];
        *(u16x8*)&Vt[((size_t)b * H_ + h * 128 + dr) * S_ + s0 + ch * 8] = o;
      }
    }
  }
}

// ---------------------------------------------------------------------------
// Kernel 2: flash attention, NO-MAX softmax (logits |s|<~2; shift = 0).
// R14-exact: BQ=64 (4 waves x 16q), BK=32, grid (8,32,2), K+V async dbuf,
// 1 barrier/iter. exp2 direct. setprio around MFMA clusters. Direct int32
// mask reads prefetched one k-tile ahead. Deferred row-sum reduction.
// V LDS swizzle key = (d>>1)&3 (bank fix, verified R14).
// ---------------------------------------------------------------------------
__global__ __launch_bounds__(256, 2) void attn_kernel(
    const unsigned short* __restrict__ Qb, const unsigned short* __restrict__ Kb,
    const unsigned short* __restrict__ Vt, const int* __restrict__ mask,
    unsigned short* __restrict__ Op, float* __restrict__ Ml,
    float* __restrict__ out) {
  __shared__ unsigned short lds[35072];   // 2*(8K K + 8K V shorts) + Ps 4*576
  unsigned short* Ps = lds + 32768;       // [wave][16 q][36]

  int t = threadIdx.x;
  int w = t >> 6, lane = t & 63, quad = lane >> 4, l15 = lane & 15;
  int b = blockIdx.x;                     // batch -> XCD affinity
  int q0 = blockIdx.y * 64;
  int split = blockIdx.z, nsplit = gridDim.z;
  int kbeg = (64 * split) / nsplit, kend = (64 * (split + 1)) / nsplit;

  s16x8 qa[8];
  {
    const unsigned short* qp =
        Qb + ((size_t)b * S_ + q0 + w * 16 + l15) * H_ + quad * 8;
#pragma unroll
    for (int c = 0; c < 8; ++c) qa[c] = *(const s16x8*)(qp + 32 * c);
  }

  const unsigned short* Kbb = Kb + (size_t)b * S_ * H_;
  const unsigned short* Vbb = Vt + (size_t)b * H_ * S_;

  int krow = lane >> 5, kch = lane & 31;
  int vrow = lane >> 2, vch = lane & 3;

  f32x4 zero4 = {0.f, 0.f, 0.f, 0.f};
  f32x4 acc[16];
#pragma unroll
  for (int i = 0; i < 16; ++i) acc[i] = zero4;
  float l_r[4] = {0.f, 0.f, 0.f, 0.f};    // per-lane partial row sums

  const int* mrow[4];
#pragma unroll
  for (int r = 0; r < 4; ++r)
    mrow[r] = mask + ((size_t)b * S_ + q0 + w * 16 + quad * 4 + r) * S_;

  {
    int k0 = kbeg * 32;
    unsigned short* Kd = lds;
    unsigned short* Vd = lds + 8192;
#pragma unroll
    for (int j = 0; j < 4; ++j) {
      int key = (w * 4 + j) * 2 + krow;
      async16(Kbb + ((size_t)(k0 + key) << 8) + ((kch ^ (key & 7)) << 3),
              Kd + (w * 4 + j) * 512);
      int d = w * 64 + j * 16 + vrow;
      async16(Vbb + ((size_t)d << 11) + k0 + ((vch ^ ((d >> 1) & 3)) << 3),
              Vd + (w * 64 + j * 16) * 32);
    }
  }
  int mw[2][4];
#pragma unroll
  for (int nf = 0; nf < 2; ++nf)
#pragma unroll
    for (int r = 0; r < 4; ++r)
      mw[nf][r] = mrow[r][kbeg * 32 + nf * 16 + l15];

  for (int kt = kbeg; kt < kend; ++kt) {
    int cur = (kt - kbeg) & 1;
    unsigned short* Ksc = lds + cur * 16384;
    unsigned short* Vsc = Ksc + 8192;
    __syncthreads();   // drains buf[cur] asyncs; buf[cur^1] free

    if (kt + 1 < kend) {
      int k0 = (kt + 1) * 32;
      unsigned short* Kd = lds + (cur ^ 1) * 16384;
      unsigned short* Vd = Kd + 8192;
#pragma unroll
      for (int j = 0; j < 4; ++j) {
        int key = (w * 4 + j) * 2 + krow;
        async16(Kbb + ((size_t)(k0 + key) << 8) + ((kch ^ (key & 7)) << 3),
                Kd + (w * 4 + j) * 512);
        int d = w * 64 + j * 16 + vrow;
        async16(Vbb + ((size_t)d << 11) + k0 + ((vch ^ ((d >> 1) & 3)) << 3),
                Vd + (w * 64 + j * 16) * 32);
      }
    }
    int mwn[2][4];
    {
      int ktn = (kt + 1 < kend) ? kt + 1 : kt;
#pragma unroll
      for (int nf = 0; nf < 2; ++nf)
#pragma unroll
        for (int r = 0; r < 4; ++r)
          mwn[nf][r] = mrow[r][ktn * 32 + nf * 16 + l15];
    }

    // ---- S = Q K^T
    f32x4 sacc[2];
    sacc[0] = zero4; sacc[1] = zero4;
    __builtin_amdgcn_s_setprio(1);
#pragma unroll
    for (int c = 0; c < 8; ++c) {
#pragma unroll
      for (int nf = 0; nf < 2; ++nf) {
        int n = nf * 16 + l15;
        s16x8 kb = *(const s16x8*)&Ksc[n * 256 + (((quad + 4 * c) ^ (n & 7)) << 3)];
        sacc[nf] = mfma_bf16(qa[c], kb, sacc[nf]);
      }
    }
    __builtin_amdgcn_s_setprio(0);

    // ---- no-max softmax: p = masked ? 0 : exp2(s); accumulate row sums
    float pvv[2][4];
#pragma unroll
    for (int r = 0; r < 4; ++r) {
#pragma unroll
      for (int nf = 0; nf < 2; ++nf) {
        float p = mw[nf][r] ? 0.f : EXP2F(sacc[nf][r]);
        pvv[nf][r] = p;
        l_r[r] += p;
      }
    }

    // ---- P -> LDS (wave-private, pitch 36: quads partition banks)
#pragma unroll
    for (int nf = 0; nf < 2; ++nf)
#pragma unroll
      for (int r = 0; r < 4; ++r) {
        int key = nf * 16 + l15;
        int ql = quad * 4 + r;
        Ps[w * 576 + ql * 36 + key] = f2bf(pvv[nf][r]);
      }

    // ---- O^T += V^T P^T (no rescale — shift is constant 0)
    {
      s16x8 bp = *(const s16x8*)&Ps[w * 576 + l15 * 36 + quad * 8];
      __builtin_amdgcn_s_setprio(1);
#pragma unroll
      for (int mf = 0; mf < 16; ++mf) {
        int d = mf * 16 + l15;
        s16x8 av = *(const s16x8*)&Vsc[d * 32 + ((quad ^ ((d >> 1) & 3)) << 3)];
        acc[mf] = mfma_bf16(av, bp, acc[mf]);
      }
      __builtin_amdgcn_s_setprio(0);
    }

#pragma unroll
    for (int nf = 0; nf < 2; ++nf)
#pragma unroll
      for (int r = 0; r < 4; ++r) mw[nf][r] = mwn[nf][r];
  }

  // ---- deferred row-sum reduction (once per kernel)
#pragma unroll
  for (int r = 0; r < 4; ++r) {
#pragma unroll
    for (int d = 1; d < 16; d <<= 1) l_r[r] += __shfl_xor(l_r[r], d, 64);
  }

  if (gridDim.z == 1) {
    float l4[4];
    int srcl = (l15 >> 2) << 4;
#pragma unroll
    for (int r = 0; r < 4; ++r) l4[r] = __shfl(l_r[r], srcl, 64);
    float lq = sel4(l4, l15 & 3);
    float linv = (lq > 0.f) ? (1.0f / lq) : 0.f;
    float* op = out + ((size_t)b * S_ + q0 + w * 16 + l15) * H_ + quad * 4;
#pragma unroll
    for (int mf = 0; mf < 16; ++mf) {
      float4 o;
      o.x = acc[mf][0] * linv; o.y = acc[mf][1] * linv;
      o.z = acc[mf][2] * linv; o.w = acc[mf][3] * linv;
      *(float4*)(op + mf * 16) = o;
    }
  } else {
    int qg = q0 + w * 16 + l15;
    unsigned short* op =
        Op + (((size_t)split * B_ + b) * S_ + qg) * H_ + quad * 4;
#pragma unroll
    for (int mf = 0; mf < 16; ++mf) {
      u16x4 pk;
      pk[0] = f2bf(acc[mf][0]); pk[1] = f2bf(acc[mf][1]);
      pk[2] = f2bf(acc[mf][2]); pk[3] = f2bf(acc[mf][3]);
      *(u16x4*)(op + mf * 16) = pk;
    }
    if (l15 == 0) {
#pragma unroll
      for (int r = 0; r < 4; ++r) {
        int qr = q0 + w * 16 + quad * 4 + r;
        Ml[((size_t)split * B_ + b) * S_ + qr] = l_r[r];
      }
    }
  }
}

// ---------------------------------------------------------------------------
// Kernel 3: combine — out = sum_i O_i / sum_i l_i.
// grid (256,8) x 1024: 8 q-rows/block, 128 threads/row, 2 d-values/thread.
// uint (2xbf16) reads + float2 writes: fully coalesced both sides.
// ---------------------------------------------------------------------------
__global__ __launch_bounds__(1024) void combine_kernel(
    const unsigned short* __restrict__ Op, const float* __restrict__ Ml,
    float* __restrict__ out, int nsplit) {
  int q = blockIdx.x * 8 + (threadIdx.x >> 7);
  int b = blockIdx.y, d0 = (threadIdx.x & 127) * 2;
  float o0 = 0.f, o1 = 0.f, lsum = 0.f;
  for (int i = 0; i < nsplit; ++i) {
    size_t ro = ((size_t)i * B_ + b) * S_ + q;
    lsum += Ml[ro];
    unsigned int v = *(const unsigned int*)&Op[ro * H_ + d0];
    o0 += bf2f((unsigned short)(v & 0xffffu));
    o1 += bf2f((unsigned short)(v >> 16));
  }
  float linv = (lsum > 0.f) ? (1.0f / lsum) : 0.f;
  float2 o;
  o.x = o0 * linv;
  o.y = o1 * linv;
  *(float2*)&out[((size_t)b * S_ + q) * H_ + d0] = o;
}

// ---------------------------------------------------------------------------
extern "C" void kernel_launch(void* const* d_in, const int* in_sizes, int n_in,
                              void* d_out, int out_size, void* d_ws, size_t ws_size,
                              hipStream_t stream) {
  const float* k_in = (const float*)d_in[0];
  const float* q_in = (const float*)d_in[1];
  const float* v_in = (const float*)d_in[2];
  const int* mask = (const int*)d_in[3];
  const float* Wq = (const float*)d_in[4];
  const float* Wk = (const float*)d_in[5];
  const float* Wv = (const float*)d_in[6];
  float* out = (float*)d_out;

  unsigned short* Qb = (unsigned short*)d_ws;
  unsigned short* Kb = Qb + (size_t)4194304;
  unsigned short* Vt = Kb + (size_t)4194304;
  unsigned short* Wt = Vt + (size_t)4194304;
  unsigned short* Op = Wt + (size_t)196608;
  float* Ml = (float*)(Op + (size_t)8388608);
  const size_t need = 42467328;
  int nsplit = (ws_size >= need) ? 2 : 1;

  hipLaunchKernelGGL(wt_kernel, dim3(48), dim3(256), 0, stream,
                     Wq, Wk, Wv, Wt);
  hipLaunchKernelGGL(proj_kernel, dim3(768), dim3(256), 0, stream,
                     q_in, k_in, v_in, Wt, Qb, Kb, Vt);
  hipLaunchKernelGGL(attn_kernel, dim3(8, 32, nsplit), dim3(256), 0, stream,
                     Qb, Kb, Vt, mask, Op, Ml, out);
  if (nsplit > 1)
    hipLaunchKernelGGL(combine_kernel, dim3(256, 8), dim3(1024), 0, stream,
                       Op, Ml, out, nsplit);
}